// Round 8
// baseline (130.661 us; speedup 1.0000x reference)
//
#include <hip/hip_runtime.h>
#include <hip/hip_bf16.h>
#include <math.h>

// Dims: B=8, T=1048576, V=257, E=8, C=128, K=512, S=512, N=64
// GEMM view: M=16384, Kdim=4096, Ncols=256.
// R8: the TLP round. 256-thread blocks = 4 waves, all sharing ONE 64x64
// output tile, 4-way K-split (wave kh does K-steps kh*4..kh*4+4). Grid
// 1024 = 256 mt x 4 nt -> 4 blocks/CU = 16 waves/CU = 4/SIMD, provided
// arch VGPRs <= 64 (+64 acc = 128 total; file ~512/SIMD). To get there:
// x is ushort-packed by prep (V=257 > 255, so ushort not uchar!), one
// int4 per rg per K-step + bfe extraction (was 64 regs of int state, now
// 16); aa/bb single-buffered (per-wave latency is covered by TLP, not by
// register pipelines). B stays L2-direct (13.7us floor), A-gathers from
// 4KB embl LDS (17us floor), MFMA 16.6us floor -> target ~30us wall.
// R4(1 wave/SIMD)=80us, R5(2)=51us; this is the first real 4/SIMD point.

typedef __bf16 bf16x8 __attribute__((ext_vector_type(8)));
typedef float  f32x4  __attribute__((ext_vector_type(4)));

// ---------------- ws layout ----------------
// [0, 2MB)      : Wp bf16 [nt=4][s'=16][t=8][q=4][n=64][e=8]
// [2MB, +8KB)   : emb bf16 [257][8]
// [4MB, +16.8MB): x16 ushort [16384][512]
#define WS_WP_OFF   0
#define WS_EMB_OFF  (2u << 20)
#define WS_X16_OFF  (4u << 20)

// ---------------------------------------------------------------------------
// prep: weight pack (bid<128), emb bf16 (bid==128), x->ushort (bid>=129).
// ---------------------------------------------------------------------------
__global__ void prep_kernel(const int* __restrict__ x,
                            const float* __restrict__ w1,
                            const float* __restrict__ w2,
                            const float* __restrict__ emb,
                            uint4* __restrict__ Wp4,
                            __bf16* __restrict__ embp,
                            unsigned short* __restrict__ x16) {
    int bid = blockIdx.x;
    int tid = threadIdx.x;
    if (bid < 128) {
        __shared__ __bf16 lds[8192];   // [(q*8+t)*32 + cl]*8 + e
        int cb = bid & 7;
        int sB = bid >> 3;
        int nt = cb >> 1, nhalf = cb & 1;
        const float* wsrc = (nhalf ? w2 : w1) + ((size_t)(nt << 5) << 12);
        int j4  = tid & 7;
        int pr0 = tid >> 3;
#pragma unroll
        for (int p = 0; p < 8; ++p) {
            int pair = p * 32 + pr0;          // 0..255 = (cl, e)
            int cl = pair >> 3, e = pair & 7;
            const float4 v = *(const float4*)(wsrc + ((size_t)cl << 12) + (e << 9) + (sB << 5) + (j4 << 2));
            float vv[4] = {v.x, v.y, v.z, v.w};
#pragma unroll
            for (int jj = 0; jj < 4; ++jj) {
                int j = (j4 << 2) + jj;        // byte_local
                int qq = j >> 3, tt = j & 7;
                lds[(((qq << 3) + tt) * 32 + cl) * 8 + e] = (__bf16)vv[jj];
            }
        }
        __syncthreads();
        const uint4* l4 = (const uint4*)lds;
        int base = (nt << 15) + (sB << 11) + (nhalf << 5);   // uint4 units
#pragma unroll
        for (int it = 0; it < 4; ++it) {
            int idx = it * 256 + tid;                         // 0..1023
            int qq = idx >> 8, tt = (idx >> 5) & 7, w = idx & 31;
            Wp4[base + (tt << 8) + (qq << 6) + w] = l4[idx];
        }
    } else if (bid == 128) {
        for (int i = tid; i < 2056; i += 256) embp[i] = (__bf16)emb[i];
    } else {
        // x pack: 8M ints -> 8M ushorts. 4096 blocks x 256 thr x 8 elems.
        size_t i0 = ((size_t)(bid - 129) << 11) + ((size_t)tid << 3);
        int4 v0 = *(const int4*)(x + i0);
        int4 v1 = *(const int4*)(x + i0 + 4);
        int4 o;
        o.x = (v0.x & 0xffff) | (v0.y << 16);
        o.y = (v0.z & 0xffff) | (v0.w << 16);
        o.z = (v1.x & 0xffff) | (v1.y << 16);
        o.w = (v1.z & 0xffff) | (v1.w << 16);
        *(int4*)(x16 + i0) = o;
    }
}

// ---------------------------------------------------------------------------
// gemm+epilogue: 256 threads = 4 waves, one 64x64 tile (4rg x 4nf), wave kh
// owns K-steps [kh*4, kh*4+4). Per t: extract 4 idx (bfe from xb int4),
// gather a[4] from embl, load b[4] from L2-resident Wp, 16 MFMAs. Single-
// buffered everything: stalls are covered by 4 waves/SIMD TLP, not unrolled
// pipelines (keeps arch VGPRs <= 64 so 4 blocks/CU actually fit).
// End: kh>0 waves dump acc to LDS in 2 chunks (24KB), kh=0 adds + gate +
// patch-max -> out. Grid 1024 = 256 mt x 4 nt; bid&7 = XCD.
// ---------------------------------------------------------------------------
__global__ __launch_bounds__(256, 4)
void gemm_kernel(const unsigned short* __restrict__ x16,
                 const __bf16* __restrict__ Wp,
                 const uint4* __restrict__ embp,
                 const float* __restrict__ b1,
                 const float* __restrict__ b2,
                 float* __restrict__ out) {
    __shared__ uint4 embl[257];
    __shared__ float mrg[3][32][64];   // 24KB: [kh-1][rh*16+nf*4+i][lane]

    const int tid  = threadIdx.x;
    const int kh   = tid >> 6;        // wave id = K quarter
    const int lane = tid & 63;
    const int q    = lane >> 4;
    const int nl   = lane & 15;

    for (int i = tid; i < 257; i += 256) embl[i] = embp[i];

    const int bid = blockIdx.x;
    const int mt = ((bid >> 5) << 3) | (bid & 7);   // 0..255
    const int nt = (bid >> 3) & 3;
    const int m0 = mt << 6;
    const int rA = m0 + nl;

    // per-lane flat B pointer: + gt*4096 + nf*256 per access
    const char* Bflat = (const char*)Wp + ((size_t)nt << 19) + (q << 10) + (nl << 4);

    // per-rg x row base (ushort units): row = rA + rg*16, + sp*32 + q*8
    const unsigned short* xq0 = x16 + ((size_t)rA << 9) + (q << 3);

    __syncthreads();   // embl ready; no barriers in main loop

    f32x4 acc[4][4] = {};
    const int sp0 = kh << 2;

    for (int ss = 0; ss < 4; ++ss) {
        const int sp = sp0 + ss;
        int4 xb[4];
#pragma unroll
        for (int rg = 0; rg < 4; ++rg)
            xb[rg] = *(const int4*)(xq0 + ((size_t)rg << 13) + (sp << 5));
#pragma unroll
        for (int t = 0; t < 8; ++t) {
            bf16x8 a[4];
#pragma unroll
            for (int rg = 0; rg < 4; ++rg) {
                int w = (t < 2) ? xb[rg].x : (t < 4) ? xb[rg].y : (t < 6) ? xb[rg].z : xb[rg].w;
                int idx = (t & 1) ? ((unsigned)w >> 16) : (w & 0xffff);
                a[rg] = *reinterpret_cast<const bf16x8*>(&embl[idx]);
            }
            const char* pb = Bflat + ((size_t)((sp << 3) + t) << 12);
            bf16x8 b[4];
#pragma unroll
            for (int nf = 0; nf < 4; ++nf)
                b[nf] = *reinterpret_cast<const bf16x8*>(pb + (nf << 8));
#pragma unroll
            for (int nf = 0; nf < 4; ++nf)
#pragma unroll
                for (int rg = 0; rg < 4; ++rg)
                    acc[rg][nf] = __builtin_amdgcn_mfma_f32_16x16x32_bf16(
                        a[rg], b[nf], acc[rg][nf], 0, 0, 0);
        }
    }

    // ---- K-quarter merge (2 chunks of 2 rg, 24KB LDS) ----
#pragma unroll
    for (int half = 0; half < 2; ++half) {
        if (kh > 0) {
#pragma unroll
            for (int rh = 0; rh < 2; ++rh)
#pragma unroll
                for (int nf = 0; nf < 4; ++nf)
#pragma unroll
                    for (int i = 0; i < 4; ++i)
                        mrg[kh - 1][(rh << 4) + (nf << 2) + i][lane] =
                            acc[(half << 1) + rh][nf][i];
        }
        __syncthreads();
        if (kh == 0) {
#pragma unroll
            for (int rh = 0; rh < 2; ++rh)
#pragma unroll
                for (int nf = 0; nf < 4; ++nf)
#pragma unroll
                    for (int i = 0; i < 4; ++i) {
                        int r = (rh << 4) + (nf << 2) + i;
                        acc[(half << 1) + rh][nf][i] +=
                            mrg[0][r][lane] + mrg[1][r][lane] + mrg[2][r][lane];
                    }
        }
        __syncthreads();
    }
    if (kh > 0) return;

    // ---- fused epilogue (kh=0 wave) ----
    // acc[rg][nf][i]: row = m0 + rg*16 + q*4 + i
    //   nf in {0,1}: c1 of channel ch = nt*32 + nf*16 + nl; nf+2: c2 same ch.
    // patch (32 rows) = mt*2 + (rg>>1); per-lane max over (rg&1, i), then
    // shfl_xor 16/32 across q-groups.
    float bb1[2], bb2[2];
#pragma unroll
    for (int nf = 0; nf < 2; ++nf) {
        int ch = (nt << 5) + (nf << 4) + nl;
        bb1[nf] = b1[ch];
        bb2[nf] = b2[ch];
    }
#pragma unroll
    for (int ph = 0; ph < 2; ++ph) {
#pragma unroll
        for (int nf = 0; nf < 2; ++nf) {
            float v = -INFINITY;
#pragma unroll
            for (int rh = 0; rh < 2; ++rh) {
                int rg = (ph << 1) + rh;
#pragma unroll
                for (int i = 0; i < 4; ++i) {
                    float c1 = acc[rg][nf][i] + bb1[nf];
                    float c2 = acc[rg][nf + 2][i] + bb2[nf];
                    float g = c1 * (1.0f / (1.0f + __expf(-c2)));
                    v = fmaxf(v, g);
                }
            }
            v = fmaxf(v, __shfl_xor(v, 16));
            v = fmaxf(v, __shfl_xor(v, 32));
            if (lane < 16) {
                int P = (mt << 1) + ph;                   // global patch id
                out[(size_t)P * 128 + (nt << 5) + (nf << 4) + nl] = v;
            }
        }
    }
}

// ---------------------------------------------------------------------------
extern "C" void kernel_launch(void* const* d_in, const int* in_sizes, int n_in,
                              void* d_out, int out_size, void* d_ws, size_t ws_size,
                              hipStream_t stream) {
    const int*   x   = (const int*)d_in[0];
    const float* emb = (const float*)d_in[1];
    const float* w1  = (const float*)d_in[2];
    const float* b1  = (const float*)d_in[3];
    const float* w2  = (const float*)d_in[4];
    const float* b2  = (const float*)d_in[5];
    float* out = (float*)d_out;

    char* ws = (char*)d_ws;
    __bf16*         Wp   = (__bf16*)(ws + WS_WP_OFF);
    __bf16*         embp = (__bf16*)(ws + WS_EMB_OFF);
    unsigned short* x16  = (unsigned short*)(ws + WS_X16_OFF);

    prep_kernel<<<129 + 4096, 256, 0, stream>>>(x, w1, w2, emb, (uint4*)Wp, embp, x16);
    gemm_kernel<<<1024, 256, 0, stream>>>(x16, Wp, (const uint4*)embp, b1, b2, out);
}